// Round 13
// baseline (99.591 us; speedup 1.0000x reference)
//
#include <hip/hip_runtime.h>
#include <math.h>

#define S 64
#define NRES 384
#define CM 256
#define CZ 128
#define NH 8
#define CH 32
#define HC 256
#define NROW 147456   // NRES*NRES

typedef unsigned short u16;
typedef __attribute__((ext_vector_type(8))) short bf16x8;
typedef __attribute__((ext_vector_type(4))) float f32x4;
typedef __attribute__((ext_vector_type(8))) unsigned short ushort8;
typedef __attribute__((ext_vector_type(4))) unsigned short ushort4_t;

// ---- workspace byte offsets ----
#define OFF_BIAS 0
#define OFF_WWT  8192
#define OFF_C1   16384
#define OFF_C2   16448
#define OFF_WT   200704
#define OFF_WOT  462848
#define OFF_A    593920
#define OFF_VT   2953216
#define OFF_G    15536128
#define OFF_O    28119040
#define OFF_MLN  40701952
#define OFF_ZB   OFF_O        // overlapped; dead before k_attn2 writes o

__device__ __forceinline__ u16 f2bf(float f) {
    union { float f; unsigned int u; } v; v.f = f;
    unsigned int u = v.u;
    u += 0x7fff + ((u >> 16) & 1);
    return (u16)(u >> 16);
}
__device__ __forceinline__ float bf2f(u16 b) {
    union { float f; unsigned int u; } v; v.u = ((unsigned int)b) << 16;
    return v.f;
}
__device__ __forceinline__ void gload16(const u16* g, u16* l) {
    __builtin_amdgcn_global_load_lds(
        (const __attribute__((address_space(1))) void*)g,
        (__attribute__((address_space(3))) void*)l, 16, 0, 0);
}

// ======  prep: bias(coalesced) | WWT/C1/C2 | Wt | Wot | mln  =================
__global__ __launch_bounds__(256) void k_pre(
        const float* __restrict__ mask, const float* __restrict__ Wz,
        const float* __restrict__ lzw, const float* __restrict__ lzb,
        const float* __restrict__ Wv, const float* __restrict__ Wg,
        const float* __restrict__ Wo, const float* __restrict__ m,
        const float* __restrict__ lmw, const float* __restrict__ lmb,
        float* __restrict__ bias, u16* __restrict__ WWT,
        float* __restrict__ C1, float* __restrict__ C2,
        u16* __restrict__ Wt, u16* __restrict__ Wot, u16* __restrict__ mln) {
    __shared__ float sRed[4][64];
    const int bid = blockIdx.x, tid = threadIdx.x;
    const int wave = tid >> 6, lane = tid & 63;
    if (bid < 6) {
        const int k = bid * 64 + lane;
        float mx = -1e30f;
        #pragma unroll
        for (int i = 0; i < 16; ++i) {
            const int s = wave * 16 + i;
            mx = fmaxf(mx, mask[(size_t)s * NRES + k]);
        }
        sRed[wave][lane] = mx;
        __syncthreads();
        if (wave == 0) {
            mx = fmaxf(fmaxf(sRed[0][lane], sRed[1][lane]),
                       fmaxf(sRed[2][lane], sRed[3][lane]));
            bias[k] = 1e9f * (mx - 1.0f);
        }
    } else if (bid == 6) {
        __shared__ float sP[2][2][8];
        if (tid < 128) {
            const int c = tid;
            const float4 wz0 = *(const float4*)&Wz[c * 8];
            const float4 wz1 = *(const float4*)&Wz[c * 8 + 4];
            const float lw = lzw[c], lbv = lzb[c];
            float wzv[8] = {wz0.x, wz0.y, wz0.z, wz0.w, wz1.x, wz1.y, wz1.z, wz1.w};
            float ww[8], wb[8];
            #pragma unroll
            for (int h = 0; h < 8; ++h) {
                ww[h] = lw * wzv[h];
                wb[h] = lbv * wzv[h];
                WWT[h * 128 + c] = f2bf(ww[h]);
                WWT[(8 + h) * 128 + c] = 0;
            }
            #pragma unroll
            for (int h = 0; h < 8; ++h) {
                #pragma unroll
                for (int off = 1; off < 64; off <<= 1) {
                    ww[h] += __shfl_xor(ww[h], off);
                    wb[h] += __shfl_xor(wb[h], off);
                }
            }
            if (lane == 0) {
                #pragma unroll
                for (int h = 0; h < 8; ++h) {
                    sP[wave][0][h] = ww[h];
                    sP[wave][1][h] = wb[h];
                }
            }
        }
        __syncthreads();
        if (tid < 8) {
            C1[tid] = sP[0][0][tid] + sP[1][0][tid];
            C2[tid] = sP[0][1][tid] + sP[1][1][tid];
        }
    } else if (bid < 519) {
        const int i = (bid - 7) * 256 + tid;
        const int n = i >> 8, k = i & 255;
        const float v = (n < HC) ? Wv[(size_t)k * HC + n] : Wg[(size_t)k * HC + (n - HC)];
        Wt[i] = f2bf(v);
    } else if (bid < 775) {
        const int i = (bid - 519) * 256 + tid;
        const int n = i >> 8, k = i & 255;
        Wot[i] = f2bf(Wo[(size_t)k * CM + n]);
    } else {
        const int row = (bid - 775) * 4 + wave;
        const float4 x = *(const float4*)&m[(size_t)row * CM + lane * 4];
        float sm = x.x + x.y + x.z + x.w;
        float sq = x.x*x.x + x.y*x.y + x.z*x.z + x.w*x.w;
        #pragma unroll
        for (int off = 32; off >= 1; off >>= 1) {
            sm += __shfl_xor(sm, off);
            sq += __shfl_xor(sq, off);
        }
        const float mu = sm * (1.0f / CM);
        const float var = sq * (1.0f / CM) - mu * mu;
        const float rs = rsqrtf(var + 1e-5f);
        const float4 w4 = *(const float4*)&lmw[lane * 4];
        const float4 b4 = *(const float4*)&lmb[lane * 4];
        u16 t4[4];
        t4[0] = f2bf((x.x - mu) * rs * w4.x + b4.x);
        t4[1] = f2bf((x.y - mu) * rs * w4.y + b4.y);
        t4[2] = f2bf((x.z - mu) * rs * w4.z + b4.z);
        t4[3] = f2bf((x.w - mu) * rs * w4.w + b4.w);
        *(ushort4_t*)&mln[(size_t)row * CM + lane * 4] = *(ushort4_t*)t4;
    }
}

// ========  mid: zb (24/32 of bids) | gemm_vg (8/32 of bids, XCD-true)  =======
// 3072 blocks. (bid&31)<24 -> zb block (bid>>5)*24+(bid&31);
// else vg block (bid>>5)*8+((bid&31)-24)  [vg bids = 0..7 mod 8 -> XCD-clean]
__global__ __launch_bounds__(256) void k_mid(
        const float* __restrict__ z, const u16* __restrict__ WWT,
        const float* __restrict__ C1, const float* __restrict__ C2,
        const u16* __restrict__ mln, const u16* __restrict__ Wt,
        float* __restrict__ zb, u16* __restrict__ vt, u16* __restrict__ g_) {
    __shared__ u16 SM[8704];           // zb: sZ 8192 u16 + stats; vg: As|Bs 8192
    const int bid = blockIdx.x, tid = threadIdx.x;
    const int wave = tid >> 6, lane = tid & 63;
    const int rl = lane & 15, kg = lane >> 4;
    const int sub = bid & 31;

    if (sub < 24) {
        // ------------------ zb: one 64-row chunk ------------------
        const int zbid = (bid >> 5) * 24 + sub;
        u16* myZ = SM + wave * 2048;
        float* sSt = (float*)(SM + 8192);     // [4][2][16]
        const int row0 = zbid * 64 + wave * 16;
        const float4* zbase = (const float4*)(z + (size_t)row0 * CZ);
        float4 xb[8];
        #pragma unroll
        for (int j = 0; j < 8; ++j) xb[j] = zbase[lane + 64 * j];
        bf16x8 bfr[4];
        #pragma unroll
        for (int t = 0; t < 4; ++t)
            bfr[t] = *(const bf16x8*)&WWT[rl * 128 + t * 32 + kg * 8];
        const float c1 = (rl < 8) ? C1[rl] : 0.f;
        const float c2 = (rl < 8) ? C2[rl] : 0.f;
        const int hw = lane >> 5, c4 = lane & 31;
        float smj[8], sqj[8];
        #pragma unroll
        for (int j = 0; j < 8; ++j) {
            const int r = 2 * j + hw;
            const float4 x = xb[j];
            float xs[4] = {x.x, x.y, x.z, x.w};
            float sm = 0.f, sq = 0.f;
            u16 t4[4];
            #pragma unroll
            for (int e = 0; e < 4; ++e) {
                sm += xs[e]; sq += xs[e] * xs[e];
                t4[e] = f2bf(xs[e]);
            }
            smj[j] = sm; sqj[j] = sq;
            *(ushort4_t*)&myZ[r * 128 + ((c4 >> 1) ^ (r & 7)) * 8 + (c4 & 1) * 4] =
                *(ushort4_t*)t4;
        }
        #pragma unroll
        for (int j = 0; j < 8; ++j) {
            #pragma unroll
            for (int off = 1; off < 32; off <<= 1) {
                smj[j] += __shfl_xor(smj[j], off);
                sqj[j] += __shfl_xor(sqj[j], off);
            }
        }
        if ((lane & 31) == 0) {
            #pragma unroll
            for (int j = 0; j < 8; ++j) {
                const int r = 2 * j + hw;
                const float mu = smj[j] * (1.0f / CZ);
                const float var = sqj[j] * (1.0f / CZ) - mu * mu;
                sSt[(wave * 2 + 0) * 16 + r] = mu;
                sSt[(wave * 2 + 1) * 16 + r] = rsqrtf(var + 1e-5f);
            }
        }
        bf16x8 af[4];
        #pragma unroll
        for (int t = 0; t < 4; ++t)
            af[t] = *(const bf16x8*)&myZ[rl * 128 + ((t * 4 + kg) ^ (rl & 7)) * 8];
        f32x4 acc = {};
        #pragma unroll
        for (int t = 0; t < 4; ++t)
            acc = __builtin_amdgcn_mfma_f32_16x16x32_bf16(af[t], bfr[t], acc, 0, 0, 0);
        f32x4 pv;
        #pragma unroll
        for (int r = 0; r < 4; ++r) {
            const int rr = kg * 4 + r;
            pv[r] = sSt[(wave * 2 + 1) * 16 + rr] *
                    (acc[r] - sSt[(wave * 2 + 0) * 16 + rr] * c1) + c2;
        }
        if (rl < 8)
            *(f32x4*)&zb[(size_t)rl * NROW + row0 + kg * 4] = pv;
        return;
    }

    // ------------------ gemm_vg: m_ln @ [Wv|Wg] ------------------
    const int vgid = (bid >> 5) * 8 + (sub - 24);
    const int xcd = vgid & 7, idx = vgid >> 3;
    const int nt = idx & 3, mt = xcd * 24 + (idx >> 2);
    const int m0 = mt * 128, n0 = nt * 128;
    const int wm = (wave >> 1) * 64, wn = (wave & 1) * 64;
    const int lr = lane >> 2, lk = (lane & 3) * 8;
    const int wr = wave * 32;
    u16* As = SM;                      // [128][32]
    u16* Bs = SM + 4096;               // [128][32]
    const u16* ag  = mln + (size_t)(m0 + wr + lr) * CM + lk;
    const u16* ag2 = ag + 16 * CM;
    const u16* bg  = Wt + (size_t)(n0 + wr + lr) * CM + lk;
    const u16* bg2 = bg + 16 * CM;
    u16* al  = As + wr * 32;
    u16* al2 = As + (wr + 16) * 32;
    u16* bl  = Bs + wr * 32;
    u16* bl2 = Bs + (wr + 16) * 32;
    const bool vhalf = (n0 < HC);
    f32x4 acc[4][4] = {};
    for (int kt = 0; kt < CM; kt += 32) {
        if (kt) __syncthreads();
        gload16(ag + kt, al);  gload16(ag2 + kt, al2);
        gload16(bg + kt, bl);  gload16(bg2 + kt, bl2);
        __syncthreads();
        bf16x8 af[4], bfr[4];
        #pragma unroll
        for (int i = 0; i < 4; ++i) af[i]  = *(const bf16x8*)&As[(wm + i*16 + rl) * 32 + kg*8];
        #pragma unroll
        for (int j = 0; j < 4; ++j) bfr[j] = *(const bf16x8*)&Bs[(wn + j*16 + rl) * 32 + kg*8];
        if (vhalf) {
            #pragma unroll
            for (int j = 0; j < 4; ++j)
                #pragma unroll
                for (int i = 0; i < 4; ++i)
                    acc[j][i] = __builtin_amdgcn_mfma_f32_16x16x32_bf16(bfr[j], af[i], acc[j][i], 0, 0, 0);
        } else {
            #pragma unroll
            for (int i = 0; i < 4; ++i)
                #pragma unroll
                for (int j = 0; j < 4; ++j)
                    acc[i][j] = __builtin_amdgcn_mfma_f32_16x16x32_bf16(af[i], bfr[j], acc[i][j], 0, 0, 0);
        }
    }
    if (vhalf) {
        #pragma unroll
        for (int j = 0; j < 4; ++j)
            #pragma unroll
            for (int r = 0; r < 4; ++r) {
                const int vcol = n0 + wn + j*16 + kg*4 + r;
                const int h = vcol >> 5, c = vcol & 31;
                #pragma unroll
                for (int i = 0; i < 4; ++i) {
                    const int mrowb = m0 + wm + i*16;
                    const int s = mrowb / NRES;
                    const int nn = mrowb - s * NRES + rl;
                    vt[(((size_t)h * S + s) * CH + c) * NRES + nn] = f2bf(acc[j][i][r]);
                }
            }
    } else {
        #pragma unroll
        for (int i = 0; i < 4; ++i)
            #pragma unroll
            for (int r = 0; r < 4; ++r) {
                const int row = m0 + wm + i*16 + kg*4 + r;
                #pragma unroll
                for (int j = 0; j < 4; ++j) {
                    const int gc = n0 + wn + j*16 + rl - HC;
                    g_[(size_t)row * HC + gc] = f2bf(1.0f / (1.0f + expf(-acc[i][j][r])));
                }
            }
    }
}

// =====================  softmax over k  ======================================
__global__ __launch_bounds__(256) void k_soft(
        const float* __restrict__ zb, const float* __restrict__ bias,
        u16* __restrict__ a_out) {
    const int w = blockIdx.x * 4 + (threadIdx.x >> 6);
    const int lane = threadIdx.x & 63;
    const int h = w & 7, q = w >> 3;
    const float* zbh = zb + (size_t)h * NROW + (size_t)q * NRES;
    float v[6];
    float mx = -1e30f;
    #pragma unroll
    for (int t = 0; t < 6; ++t) {
        const int k = lane + 64 * t;
        v[t] = zbh[k] + bias[k];
        mx = fmaxf(mx, v[t]);
    }
    #pragma unroll
    for (int off = 32; off >= 1; off >>= 1) mx = fmaxf(mx, __shfl_xor(mx, off));
    float sum = 0.f;
    #pragma unroll
    for (int t = 0; t < 6; ++t) { v[t] = expf(v[t] - mx); sum += v[t]; }
    #pragma unroll
    for (int off = 32; off >= 1; off >>= 1) sum += __shfl_xor(sum, off);
    const float inv = 1.0f / sum;
    #pragma unroll
    for (int t = 0; t < 6; ++t)
        a_out[((size_t)h * NRES + q) * NRES + lane + 64 * t] = f2bf(v[t] * inv);
}

// ========== attn as per-h GEMM (one head per XCD), gload_lds staging =========
__global__ __launch_bounds__(256) void k_attn2(const u16* __restrict__ a_,
        const u16* __restrict__ vt, u16* __restrict__ o_) {
    __shared__ u16 As[128][32];
    __shared__ u16 Bs[128][32];
    const int tid = threadIdx.x;
    const int h = blockIdx.x & 7, rem = blockIdx.x >> 3;
    const int mt = rem >> 4, nt = rem & 15;
    const int q0 = mt * 128, sc0 = nt * 128;
    const int wave = tid >> 6, lane = tid & 63;
    const int wm = (wave >> 1) * 64, wn = (wave & 1) * 64;
    const int rl = lane & 15, kg = lane >> 4;
    const int lr = lane >> 2, lk = (lane & 3) * 8;
    const int wr = wave * 32;
    const u16* ag  = a_ + (size_t)h * NRES * NRES + (size_t)(q0 + wr + lr) * NRES + lk;
    const u16* ag2 = ag + 16 * NRES;
    const u16* bg  = vt + (size_t)h * S * CH * NRES + (size_t)(sc0 + wr + lr) * NRES + lk;
    const u16* bg2 = bg + 16 * NRES;
    u16* al  = &As[wr][0];
    u16* al2 = &As[wr + 16][0];
    u16* bl  = &Bs[wr][0];
    u16* bl2 = &Bs[wr + 16][0];
    f32x4 acc[4][4] = {};
    for (int kt = 0; kt < NRES; kt += 32) {
        if (kt) __syncthreads();
        gload16(ag + kt, al);  gload16(ag2 + kt, al2);
        gload16(bg + kt, bl);  gload16(bg2 + kt, bl2);
        __syncthreads();
        bf16x8 af[4], bfr[4];
        #pragma unroll
        for (int i = 0; i < 4; ++i) af[i]  = *(const bf16x8*)&As[wm + i*16 + rl][kg*8];
        #pragma unroll
        for (int j = 0; j < 4; ++j) bfr[j] = *(const bf16x8*)&Bs[wn + j*16 + rl][kg*8];
        #pragma unroll
        for (int i = 0; i < 4; ++i)
            #pragma unroll
            for (int j = 0; j < 4; ++j)
                acc[i][j] = __builtin_amdgcn_mfma_f32_16x16x32_bf16(af[i], bfr[j], acc[i][j], 0, 0, 0);
    }
    #pragma unroll
    for (int i = 0; i < 4; ++i)
        #pragma unroll
        for (int r = 0; r < 4; ++r) {
            const int q = q0 + wm + i*16 + kg*4 + r;
            #pragma unroll
            for (int j = 0; j < 4; ++j) {
                const int sc = sc0 + wn + j*16 + rl;
                const int s = sc >> 5, c = sc & 31;
                o_[(((size_t)s * NRES + q) * NH + h) * CH + c] = f2bf(acc[i][j][r]);
            }
        }
}

// ========== out = (o*g) @ Wo  (XCD-swizzled, B via gload_lds) ================
__global__ __launch_bounds__(256) void k_gemm_out(const u16* __restrict__ o_,
        const u16* __restrict__ g_, const u16* __restrict__ Wot,
        float* __restrict__ out) {
    __shared__ u16 As[128][40];
    __shared__ u16 Bs[128][32];
    const int tid = threadIdx.x;
    const int xcd = blockIdx.x & 7, idx = blockIdx.x >> 3;
    const int nt = idx & 1, mt = xcd * 24 + (idx >> 1);
    const int m0 = mt * 128, n0 = nt * 128;
    const int wave = tid >> 6, lane = tid & 63;
    const int wm = (wave >> 1) * 64, wn = (wave & 1) * 64;
    const int rl = lane & 15, kg = lane >> 4;
    const int lr = lane >> 2, lk = (lane & 3) * 8;
    const int wr = wave * 32;
    const int sr = tid >> 1, sh = (tid & 1) * 16;
    const u16* orow = o_ + (size_t)(m0 + sr) * HC;
    const u16* grow = g_ + (size_t)(m0 + sr) * HC;
    const u16* bg  = Wot + (size_t)(n0 + wr + lr) * HC + lk;
    const u16* bg2 = bg + 16 * HC;
    u16* bl  = &Bs[wr][0];
    u16* bl2 = &Bs[wr + 16][0];
    f32x4 acc[4][4] = {};
    for (int kt = 0; kt < HC; kt += 32) {
        if (kt) __syncthreads();
        gload16(bg + kt, bl);  gload16(bg2 + kt, bl2);
        {
            u16 tmp[16];
            const ushort8 ov0 = *(const ushort8*)&orow[kt + sh];
            const ushort8 ov1 = *(const ushort8*)&orow[kt + sh + 8];
            const ushort8 gv0 = *(const ushort8*)&grow[kt + sh];
            const ushort8 gv1 = *(const ushort8*)&grow[kt + sh + 8];
            #pragma unroll
            for (int p = 0; p < 8; ++p) {
                tmp[p]     = f2bf(bf2f(ov0[p]) * bf2f(gv0[p]));
                tmp[p + 8] = f2bf(bf2f(ov1[p]) * bf2f(gv1[p]));
            }
            *(ushort8*)&As[sr][sh]     = *(ushort8*)&tmp[0];
            *(ushort8*)&As[sr][sh + 8] = *(ushort8*)&tmp[8];
        }
        __syncthreads();
        bf16x8 af[4], bfr[4];
        #pragma unroll
        for (int i = 0; i < 4; ++i) af[i]  = *(const bf16x8*)&As[wm + i*16 + rl][kg*8];
        #pragma unroll
        for (int j = 0; j < 4; ++j) bfr[j] = *(const bf16x8*)&Bs[wn + j*16 + rl][kg*8];
        #pragma unroll
        for (int i = 0; i < 4; ++i)
            #pragma unroll
            for (int j = 0; j < 4; ++j)
                acc[i][j] = __builtin_amdgcn_mfma_f32_16x16x32_bf16(af[i], bfr[j], acc[i][j], 0, 0, 0);
    }
    #pragma unroll
    for (int i = 0; i < 4; ++i)
        #pragma unroll
        for (int r = 0; r < 4; ++r) {
            const int row = m0 + wm + i*16 + kg*4 + r;
            #pragma unroll
            for (int j = 0; j < 4; ++j)
                out[(size_t)row * CM + n0 + wn + j*16 + rl] = acc[i][j][r];
        }
}

extern "C" void kernel_launch(void* const* d_in, const int* in_sizes, int n_in,
                              void* d_out, int out_size, void* d_ws, size_t ws_size,
                              hipStream_t stream) {
    const float* m      = (const float*)d_in[0];
    const float* z      = (const float*)d_in[1];
    const float* mask   = (const float*)d_in[2];
    const float* ln_m_w = (const float*)d_in[3];
    const float* ln_m_b = (const float*)d_in[4];
    const float* ln_z_w = (const float*)d_in[5];
    const float* ln_z_b = (const float*)d_in[6];
    const float* Wz     = (const float*)d_in[7];
    const float* Wv     = (const float*)d_in[8];
    const float* Wg     = (const float*)d_in[9];
    const float* Wo     = (const float*)d_in[10];
    float* out = (float*)d_out;
    char* ws = (char*)d_ws;

    float* bias = (float*)(ws + OFF_BIAS);
    u16* WWT    = (u16*)(ws + OFF_WWT);
    float* C1   = (float*)(ws + OFF_C1);
    float* C2   = (float*)(ws + OFF_C2);
    u16* Wt     = (u16*)(ws + OFF_WT);
    u16* Wot    = (u16*)(ws + OFF_WOT);
    u16* a      = (u16*)(ws + OFF_A);
    u16* vtw    = (u16*)(ws + OFF_VT);
    u16* gw     = (u16*)(ws + OFF_G);
    u16* ow     = (u16*)(ws + OFF_O);
    u16* mlnw   = (u16*)(ws + OFF_MLN);
    float* zbw  = (float*)(ws + OFF_ZB);

    k_pre<<<6919, 256, 0, stream>>>(mask, Wz, ln_z_w, ln_z_b, Wv, Wg, Wo, m,
                                    ln_m_w, ln_m_b, bias, WWT, C1, C2, Wt, Wot, mlnw);
    k_mid<<<3072, 256, 0, stream>>>(z, WWT, C1, C2, mlnw, Wt, zbw, vtw, gw);
    k_soft<<<768, 256, 0, stream>>>(zbw, bias, a);
    k_attn2<<<384, 256, 0, stream>>>(a, vtw, ow);
    k_gemm_out<<<384, 256, 0, stream>>>(ow, gw, Wot, out);
}

// Round 14
// 73.476 us; speedup vs baseline: 1.3554x; 1.3554x over previous
//
#include <hip/hip_runtime.h>
#include <math.h>

#define S 64
#define NRES 384
#define CM 256
#define CZ 128
#define NH 8
#define CH 32
#define HC 256
#define NROW 147456   // NRES*NRES

typedef unsigned short u16;
typedef __attribute__((ext_vector_type(8))) short bf16x8;
typedef __attribute__((ext_vector_type(4))) float f32x4;
typedef __attribute__((ext_vector_type(8))) unsigned short ushort8;
typedef __attribute__((ext_vector_type(4))) unsigned short ushort4_t;

// ---- workspace byte offsets ----
#define OFF_BIAS 0
#define OFF_WT   200704
#define OFF_WOT  462848
#define OFF_A    593920
#define OFF_VT   2953216
#define OFF_G    15536128
#define OFF_O    28119040
#define OFF_MLN  40701952
#define OFF_ZB   OFF_O        // overlapped; dead before k_attn2 writes o

__device__ __forceinline__ u16 f2bf(float f) {
    union { float f; unsigned int u; } v; v.f = f;
    unsigned int u = v.u;
    u += 0x7fff + ((u >> 16) & 1);
    return (u16)(u >> 16);
}
__device__ __forceinline__ float bf2f(u16 b) {
    union { float f; unsigned int u; } v; v.u = ((unsigned int)b) << 16;
    return v.f;
}
__device__ __forceinline__ void gload16(const u16* g, u16* l) {
    __builtin_amdgcn_global_load_lds(
        (const __attribute__((address_space(1))) void*)g,
        (__attribute__((address_space(3))) void*)l, 16, 0, 0);
}

// ====  front: zb(self-sufficient, LN-in-A) | bias | Wt | Wot | mln  ==========
// blocks: [0,2304) zb; [2304,2310) bias; [2310,2822) Wt; [2822,3078) Wot;
//         [3078,9222) m_ln.  All branches independent (no intra-launch deps).
// zb math: logit-equiv[row,h] = sum_c bf16((z-mu)*rs)_c * bf16(lzw_c*Wz[c,h]).
// The lb@Wz term (C2[h]) is constant over k -> dropped (softmax shift-invar.)
__global__ __launch_bounds__(256) void k_front(
        const float* __restrict__ z, const float* __restrict__ Wz,
        const float* __restrict__ lzw,
        const float* __restrict__ mask,
        const float* __restrict__ Wv, const float* __restrict__ Wg,
        const float* __restrict__ Wo, const float* __restrict__ m,
        const float* __restrict__ lmw, const float* __restrict__ lmb,
        float* __restrict__ zb, float* __restrict__ bias,
        u16* __restrict__ Wt, u16* __restrict__ Wot, u16* __restrict__ mln) {
    __shared__ u16 SMEM[2048 + 4 * 2048];   // sW [16][128] + 4x wave-private sZ
    const int bid = blockIdx.x, tid = threadIdx.x;
    const int wave = tid >> 6, lane = tid & 63;
    const int rl = lane & 15, kg = lane >> 4;

    if (bid < 2304) {
        u16* sW  = SMEM;                    // [16][128] bf16: lzw*Wz, rows 8-15 zero
        u16* myZ = SMEM + 2048 + wave * 2048;
        // ---- stage WW (4KB, coalesced, L2-hot) ----
        if (tid < 128) {
            const int c = tid;
            const float4 wz0 = *(const float4*)&Wz[c * 8];
            const float4 wz1 = *(const float4*)&Wz[c * 8 + 4];
            const float lw = lzw[c];
            float wzv[8] = {wz0.x, wz0.y, wz0.z, wz0.w, wz1.x, wz1.y, wz1.z, wz1.w};
            #pragma unroll
            for (int h = 0; h < 8; ++h) {
                sW[h * 128 + c] = f2bf(lw * wzv[h]);
                sW[(8 + h) * 128 + c] = 0;
            }
        }
        // ---- 8 perfectly-coalesced z loads (issued before the barrier) ----
        const int row0 = bid * 64 + wave * 16;
        const float4* zbase = (const float4*)(z + (size_t)row0 * CZ);
        float4 xb[8];
        #pragma unroll
        for (int j = 0; j < 8; ++j) xb[j] = zbase[lane + 64 * j];
        __syncthreads();
        bf16x8 bfr[4];
        #pragma unroll
        for (int t = 0; t < 4; ++t)
            bfr[t] = *(const bf16x8*)&sW[rl * 128 + t * 32 + kg * 8];
        // ---- exact f32 stats: lane's float4 j belongs to row 2j+(lane>>5) ----
        const int hw = lane >> 5, c4 = lane & 31;
        float smj[8], sqj[8];
        #pragma unroll
        for (int j = 0; j < 8; ++j) {
            const float4 x = xb[j];
            smj[j] = x.x + x.y + x.z + x.w;
            sqj[j] = x.x*x.x + x.y*x.y + x.z*x.z + x.w*x.w;
        }
        #pragma unroll
        for (int j = 0; j < 8; ++j) {
            #pragma unroll
            for (int off = 1; off < 32; off <<= 1) {
                smj[j] += __shfl_xor(smj[j], off);
                sqj[j] += __shfl_xor(sqj[j], off);
            }
        }
        // ---- normalize in-register, convert, swizzled LDS store ----
        #pragma unroll
        for (int j = 0; j < 8; ++j) {
            const int r = 2 * j + hw;
            const float mu = smj[j] * (1.0f / CZ);
            const float var = sqj[j] * (1.0f / CZ) - mu * mu;
            const float rs = rsqrtf(var + 1e-5f);
            const float4 x = xb[j];
            u16 t4[4];
            t4[0] = f2bf((x.x - mu) * rs);
            t4[1] = f2bf((x.y - mu) * rs);
            t4[2] = f2bf((x.z - mu) * rs);
            t4[3] = f2bf((x.w - mu) * rs);
            *(ushort4_t*)&myZ[r * 128 + ((c4 >> 1) ^ (r & 7)) * 8 + (c4 & 1) * 4] =
                *(ushort4_t*)t4;
        }
        // ---- A-frags from swizzled LDS + MFMA; raw acc IS the logit ----
        bf16x8 af[4];
        #pragma unroll
        for (int t = 0; t < 4; ++t)
            af[t] = *(const bf16x8*)&myZ[rl * 128 + ((t * 4 + kg) ^ (rl & 7)) * 8];
        f32x4 acc = {};
        #pragma unroll
        for (int t = 0; t < 4; ++t)
            acc = __builtin_amdgcn_mfma_f32_16x16x32_bf16(af[t], bfr[t], acc, 0, 0, 0);
        if (rl < 8)
            *(f32x4*)&zb[(size_t)rl * NROW + row0 + kg * 4] = acc;
    } else if (bid < 2310) {
        float* sRed = (float*)SMEM;        // [4][64]
        const int k = (bid - 2304) * 64 + lane;
        float mx = -1e30f;
        #pragma unroll
        for (int i = 0; i < 16; ++i) {
            const int s = wave * 16 + i;
            mx = fmaxf(mx, mask[(size_t)s * NRES + k]);
        }
        sRed[wave * 64 + lane] = mx;
        __syncthreads();
        if (wave == 0) {
            mx = fmaxf(fmaxf(sRed[lane], sRed[64 + lane]),
                       fmaxf(sRed[128 + lane], sRed[192 + lane]));
            bias[k] = 1e9f * (mx - 1.0f);
        }
    } else if (bid < 2822) {
        const int i = (bid - 2310) * 256 + tid;
        const int n = i >> 8, k = i & 255;
        const float v = (n < HC) ? Wv[(size_t)k * HC + n] : Wg[(size_t)k * HC + (n - HC)];
        Wt[i] = f2bf(v);
    } else if (bid < 3078) {
        const int i = (bid - 2822) * 256 + tid;
        const int n = i >> 8, k = i & 255;
        Wot[i] = f2bf(Wo[(size_t)k * CM + n]);
    } else {
        const int row = (bid - 3078) * 4 + wave;
        const float4 x = *(const float4*)&m[(size_t)row * CM + lane * 4];
        float sm = x.x + x.y + x.z + x.w;
        float sq = x.x*x.x + x.y*x.y + x.z*x.z + x.w*x.w;
        #pragma unroll
        for (int off = 32; off >= 1; off >>= 1) {
            sm += __shfl_xor(sm, off);
            sq += __shfl_xor(sq, off);
        }
        const float mu = sm * (1.0f / CM);
        const float var = sq * (1.0f / CM) - mu * mu;
        const float rs = rsqrtf(var + 1e-5f);
        const float4 w4 = *(const float4*)&lmw[lane * 4];
        const float4 b4 = *(const float4*)&lmb[lane * 4];
        u16 t4[4];
        t4[0] = f2bf((x.x - mu) * rs * w4.x + b4.x);
        t4[1] = f2bf((x.y - mu) * rs * w4.y + b4.y);
        t4[2] = f2bf((x.z - mu) * rs * w4.z + b4.z);
        t4[3] = f2bf((x.w - mu) * rs * w4.w + b4.w);
        *(ushort4_t*)&mln[(size_t)row * CM + lane * 4] = *(ushort4_t*)t4;
    }
}

// =====================  stage 2: gemm_vg | soft  =============================
__global__ __launch_bounds__(256) void k_stage2(
        const u16* __restrict__ mln, const u16* __restrict__ Wt,
        const float* __restrict__ zb, const float* __restrict__ bias,
        u16* __restrict__ vt, u16* __restrict__ g_, u16* __restrict__ a_out) {
    __shared__ u16 As[128][32];
    __shared__ u16 Bs[128][32];
    const int bid = blockIdx.x, tid = threadIdx.x;
    if (bid >= 768) {
        const int w = (bid - 768) * 4 + (tid >> 6);
        const int lane = tid & 63;
        const int h = w & 7, q = w >> 3;
        const float* zbh = zb + (size_t)h * NROW + (size_t)q * NRES;
        float v[6];
        float mx = -1e30f;
        #pragma unroll
        for (int t = 0; t < 6; ++t) {
            const int k = lane + 64 * t;
            v[t] = zbh[k] + bias[k];
            mx = fmaxf(mx, v[t]);
        }
        #pragma unroll
        for (int off = 32; off >= 1; off >>= 1) mx = fmaxf(mx, __shfl_xor(mx, off));
        float sum = 0.f;
        #pragma unroll
        for (int t = 0; t < 6; ++t) { v[t] = expf(v[t] - mx); sum += v[t]; }
        #pragma unroll
        for (int off = 32; off >= 1; off >>= 1) sum += __shfl_xor(sum, off);
        const float inv = 1.0f / sum;
        #pragma unroll
        for (int t = 0; t < 6; ++t)
            a_out[((size_t)h * NRES + q) * NRES + lane + 64 * t] = f2bf(v[t] * inv);
        return;
    }
    const int xcd = bid & 7, idx = bid >> 3;
    const int nt = idx & 3, mt = xcd * 24 + (idx >> 2);
    const int m0 = mt * 128, n0 = nt * 128;
    const int wave = tid >> 6, lane = tid & 63;
    const int wm = (wave >> 1) * 64, wn = (wave & 1) * 64;
    const int rl = lane & 15, kg = lane >> 4;
    const int lr = lane >> 2, lk = (lane & 3) * 8;
    const int wr = wave * 32;
    const u16* ag  = mln + (size_t)(m0 + wr + lr) * CM + lk;
    const u16* ag2 = ag + 16 * CM;
    const u16* bg  = Wt + (size_t)(n0 + wr + lr) * CM + lk;
    const u16* bg2 = bg + 16 * CM;
    u16* al  = &As[wr][0];
    u16* al2 = &As[wr + 16][0];
    u16* bl  = &Bs[wr][0];
    u16* bl2 = &Bs[wr + 16][0];
    const bool vhalf = (n0 < HC);
    f32x4 acc[4][4] = {};
    for (int kt = 0; kt < CM; kt += 32) {
        if (kt) __syncthreads();
        gload16(ag + kt, al);  gload16(ag2 + kt, al2);
        gload16(bg + kt, bl);  gload16(bg2 + kt, bl2);
        __syncthreads();
        bf16x8 af[4], bfr[4];
        #pragma unroll
        for (int i = 0; i < 4; ++i) af[i]  = *(const bf16x8*)&As[wm + i*16 + rl][kg*8];
        #pragma unroll
        for (int j = 0; j < 4; ++j) bfr[j] = *(const bf16x8*)&Bs[wn + j*16 + rl][kg*8];
        if (vhalf) {
            #pragma unroll
            for (int j = 0; j < 4; ++j)
                #pragma unroll
                for (int i = 0; i < 4; ++i)
                    acc[j][i] = __builtin_amdgcn_mfma_f32_16x16x32_bf16(bfr[j], af[i], acc[j][i], 0, 0, 0);
        } else {
            #pragma unroll
            for (int i = 0; i < 4; ++i)
                #pragma unroll
                for (int j = 0; j < 4; ++j)
                    acc[i][j] = __builtin_amdgcn_mfma_f32_16x16x32_bf16(af[i], bfr[j], acc[i][j], 0, 0, 0);
        }
    }
    if (vhalf) {
        #pragma unroll
        for (int j = 0; j < 4; ++j)
            #pragma unroll
            for (int r = 0; r < 4; ++r) {
                const int vcol = n0 + wn + j*16 + kg*4 + r;
                const int h = vcol >> 5, c = vcol & 31;
                #pragma unroll
                for (int i = 0; i < 4; ++i) {
                    const int mrowb = m0 + wm + i*16;
                    const int s = mrowb / NRES;
                    const int nn = mrowb - s * NRES + rl;
                    vt[(((size_t)h * S + s) * CH + c) * NRES + nn] = f2bf(acc[j][i][r]);
                }
            }
    } else {
        #pragma unroll
        for (int i = 0; i < 4; ++i)
            #pragma unroll
            for (int r = 0; r < 4; ++r) {
                const int row = m0 + wm + i*16 + kg*4 + r;
                #pragma unroll
                for (int j = 0; j < 4; ++j) {
                    const int gc = n0 + wn + j*16 + rl - HC;
                    g_[(size_t)row * HC + gc] = f2bf(1.0f / (1.0f + expf(-acc[i][j][r])));
                }
            }
    }
}

// ========== attn as per-h GEMM (one head per XCD), gload_lds staging =========
__global__ __launch_bounds__(256) void k_attn2(const u16* __restrict__ a_,
        const u16* __restrict__ vt, u16* __restrict__ o_) {
    __shared__ u16 As[128][32];
    __shared__ u16 Bs[128][32];
    const int tid = threadIdx.x;
    const int h = blockIdx.x & 7, rem = blockIdx.x >> 3;
    const int mt = rem >> 4, nt = rem & 15;
    const int q0 = mt * 128, sc0 = nt * 128;
    const int wave = tid >> 6, lane = tid & 63;
    const int wm = (wave >> 1) * 64, wn = (wave & 1) * 64;
    const int rl = lane & 15, kg = lane >> 4;
    const int lr = lane >> 2, lk = (lane & 3) * 8;
    const int wr = wave * 32;
    const u16* ag  = a_ + (size_t)h * NRES * NRES + (size_t)(q0 + wr + lr) * NRES + lk;
    const u16* ag2 = ag + 16 * NRES;
    const u16* bg  = vt + (size_t)h * S * CH * NRES + (size_t)(sc0 + wr + lr) * NRES + lk;
    const u16* bg2 = bg + 16 * NRES;
    u16* al  = &As[wr][0];
    u16* al2 = &As[wr + 16][0];
    u16* bl  = &Bs[wr][0];
    u16* bl2 = &Bs[wr + 16][0];
    f32x4 acc[4][4] = {};
    for (int kt = 0; kt < NRES; kt += 32) {
        if (kt) __syncthreads();
        gload16(ag + kt, al);  gload16(ag2 + kt, al2);
        gload16(bg + kt, bl);  gload16(bg2 + kt, bl2);
        __syncthreads();
        bf16x8 af[4], bfr[4];
        #pragma unroll
        for (int i = 0; i < 4; ++i) af[i]  = *(const bf16x8*)&As[wm + i*16 + rl][kg*8];
        #pragma unroll
        for (int j = 0; j < 4; ++j) bfr[j] = *(const bf16x8*)&Bs[wn + j*16 + rl][kg*8];
        #pragma unroll
        for (int i = 0; i < 4; ++i)
            #pragma unroll
            for (int j = 0; j < 4; ++j)
                acc[i][j] = __builtin_amdgcn_mfma_f32_16x16x32_bf16(af[i], bfr[j], acc[i][j], 0, 0, 0);
    }
    #pragma unroll
    for (int i = 0; i < 4; ++i)
        #pragma unroll
        for (int r = 0; r < 4; ++r) {
            const int q = q0 + wm + i*16 + kg*4 + r;
            #pragma unroll
            for (int j = 0; j < 4; ++j) {
                const int sc = sc0 + wn + j*16 + rl;
                const int s = sc >> 5, c = sc & 31;
                o_[(((size_t)s * NRES + q) * NH + h) * CH + c] = f2bf(acc[i][j][r]);
            }
        }
}

// ========== out = (o*g) @ Wo  (XCD-swizzled, B via gload_lds) ================
__global__ __launch_bounds__(256) void k_gemm_out(const u16* __restrict__ o_,
        const u16* __restrict__ g_, const u16* __restrict__ Wot,
        float* __restrict__ out) {
    __shared__ u16 As[128][40];
    __shared__ u16 Bs[128][32];
    const int tid = threadIdx.x;
    const int xcd = blockIdx.x & 7, idx = blockIdx.x >> 3;
    const int nt = idx & 1, mt = xcd * 24 + (idx >> 1);
    const int m0 = mt * 128, n0 = nt * 128;
    const int wave = tid >> 6, lane = tid & 63;
    const int wm = (wave >> 1) * 64, wn = (wave & 1) * 64;
    const int rl = lane & 15, kg = lane >> 4;
    const int lr = lane >> 2, lk = (lane & 3) * 8;
    const int wr = wave * 32;
    const int sr = tid >> 1, sh = (tid & 1) * 16;
    const u16* orow = o_ + (size_t)(m0 + sr) * HC;
    const u16* grow = g_ + (size_t)(m0 + sr) * HC;
    const u16* bg  = Wot + (size_t)(n0 + wr + lr) * HC + lk;
    const u16* bg2 = bg + 16 * HC;
    u16* bl  = &Bs[wr][0];
    u16* bl2 = &Bs[wr + 16][0];
    f32x4 acc[4][4] = {};
    for (int kt = 0; kt < HC; kt += 32) {
        if (kt) __syncthreads();
        gload16(bg + kt, bl);  gload16(bg2 + kt, bl2);
        {
            u16 tmp[16];
            const ushort8 ov0 = *(const ushort8*)&orow[kt + sh];
            const ushort8 ov1 = *(const ushort8*)&orow[kt + sh + 8];
            const ushort8 gv0 = *(const ushort8*)&grow[kt + sh];
            const ushort8 gv1 = *(const ushort8*)&grow[kt + sh + 8];
            #pragma unroll
            for (int p = 0; p < 8; ++p) {
                tmp[p]     = f2bf(bf2f(ov0[p]) * bf2f(gv0[p]));
                tmp[p + 8] = f2bf(bf2f(ov1[p]) * bf2f(gv1[p]));
            }
            *(ushort8*)&As[sr][sh]     = *(ushort8*)&tmp[0];
            *(ushort8*)&As[sr][sh + 8] = *(ushort8*)&tmp[8];
        }
        __syncthreads();
        bf16x8 af[4], bfr[4];
        #pragma unroll
        for (int i = 0; i < 4; ++i) af[i]  = *(const bf16x8*)&As[wm + i*16 + rl][kg*8];
        #pragma unroll
        for (int j = 0; j < 4; ++j) bfr[j] = *(const bf16x8*)&Bs[wn + j*16 + rl][kg*8];
        #pragma unroll
        for (int i = 0; i < 4; ++i)
            #pragma unroll
            for (int j = 0; j < 4; ++j)
                acc[i][j] = __builtin_amdgcn_mfma_f32_16x16x32_bf16(af[i], bfr[j], acc[i][j], 0, 0, 0);
    }
    #pragma unroll
    for (int i = 0; i < 4; ++i)
        #pragma unroll
        for (int r = 0; r < 4; ++r) {
            const int row = m0 + wm + i*16 + kg*4 + r;
            #pragma unroll
            for (int j = 0; j < 4; ++j)
                out[(size_t)row * CM + n0 + wn + j*16 + rl] = acc[i][j][r];
        }
}

extern "C" void kernel_launch(void* const* d_in, const int* in_sizes, int n_in,
                              void* d_out, int out_size, void* d_ws, size_t ws_size,
                              hipStream_t stream) {
    const float* m      = (const float*)d_in[0];
    const float* z      = (const float*)d_in[1];
    const float* mask   = (const float*)d_in[2];
    const float* ln_m_w = (const float*)d_in[3];
    const float* ln_m_b = (const float*)d_in[4];
    const float* ln_z_w = (const float*)d_in[5];
    const float* Wz     = (const float*)d_in[7];
    const float* Wv     = (const float*)d_in[8];
    const float* Wg     = (const float*)d_in[9];
    const float* Wo     = (const float*)d_in[10];
    float* out = (float*)d_out;
    char* ws = (char*)d_ws;

    float* bias = (float*)(ws + OFF_BIAS);
    u16* Wt     = (u16*)(ws + OFF_WT);
    u16* Wot    = (u16*)(ws + OFF_WOT);
    u16* a      = (u16*)(ws + OFF_A);
    u16* vtw    = (u16*)(ws + OFF_VT);
    u16* gw     = (u16*)(ws + OFF_G);
    u16* ow     = (u16*)(ws + OFF_O);
    u16* mlnw   = (u16*)(ws + OFF_MLN);
    float* zbw  = (float*)(ws + OFF_ZB);

    k_front<<<9222, 256, 0, stream>>>(z, Wz, ln_z_w, mask, Wv, Wg, Wo, m,
                                      ln_m_w, ln_m_b, zbw, bias, Wt, Wot, mlnw);
    k_stage2<<<1536, 256, 0, stream>>>(mlnw, Wt, zbw, bias, vtw, gw, a);
    k_attn2<<<384, 256, 0, stream>>>(a, vtw, ow);
    k_gemm_out<<<384, 256, 0, stream>>>(ow, gw, Wot, out);
}

// Round 15
// 72.409 us; speedup vs baseline: 1.3754x; 1.0147x over previous
//
#include <hip/hip_runtime.h>
#include <math.h>

#define S 64
#define NRES 384
#define CM 256
#define CZ 128
#define NH 8
#define CH 32
#define HC 256
#define NROW 147456   // NRES*NRES

typedef unsigned short u16;
typedef __attribute__((ext_vector_type(8))) short bf16x8;
typedef __attribute__((ext_vector_type(4))) float f32x4;
typedef __attribute__((ext_vector_type(8))) unsigned short ushort8;
typedef __attribute__((ext_vector_type(4))) unsigned short ushort4_t;

// ---- workspace byte offsets ----
#define OFF_BIAS 0
#define OFF_WT   200704
#define OFF_WOT  462848
#define OFF_A    593920
#define OFF_VT   2953216
#define OFF_G    15536128
#define OFF_O    28119040
#define OFF_MLN  40701952
#define OFF_ZB   OFF_O        // overlapped; dead before k_attn2 writes o

__device__ __forceinline__ u16 f2bf(float f) {
    union { float f; unsigned int u; } v; v.f = f;
    unsigned int u = v.u;
    u += 0x7fff + ((u >> 16) & 1);
    return (u16)(u >> 16);
}
__device__ __forceinline__ float bf2f(u16 b) {
    union { float f; unsigned int u; } v; v.u = ((unsigned int)b) << 16;
    return v.f;
}
__device__ __forceinline__ void gload16(const u16* g, u16* l) {
    __builtin_amdgcn_global_load_lds(
        (const __attribute__((address_space(1))) void*)g,
        (__attribute__((address_space(3))) void*)l, 16, 0, 0);
}

// ====  front: zb(self-sufficient, LN-in-A) | bias | Wt | Wot | mln  ==========
// blocks: [0,2304) zb; [2304,2310) bias; [2310,2822) Wt; [2822,3078) Wot;
//         [3078,6150) m_ln (8 rows/block, 32B/lane).
__global__ __launch_bounds__(256) void k_front(
        const float* __restrict__ z, const float* __restrict__ Wz,
        const float* __restrict__ lzw,
        const float* __restrict__ mask,
        const float* __restrict__ Wv, const float* __restrict__ Wg,
        const float* __restrict__ Wo, const float* __restrict__ m,
        const float* __restrict__ lmw, const float* __restrict__ lmb,
        float* __restrict__ zb, float* __restrict__ bias,
        u16* __restrict__ Wt, u16* __restrict__ Wot, u16* __restrict__ mln) {
    __shared__ u16 SMEM[2048 + 4 * 2048];   // sW [16][128] + 4x wave-private sZ
    const int bid = blockIdx.x, tid = threadIdx.x;
    const int wave = tid >> 6, lane = tid & 63;
    const int rl = lane & 15, kg = lane >> 4;

    if (bid < 2304) {
        u16* sW  = SMEM;                    // [16][128] bf16: lzw*Wz, rows 8-15 zero
        u16* myZ = SMEM + 2048 + wave * 2048;
        // ---- z loads FIRST (the critical HBM stream; Wz is L2-hot) ----
        const int row0 = bid * 64 + wave * 16;
        const float4* zbase = (const float4*)(z + (size_t)row0 * CZ);
        float4 xb[8];
        #pragma unroll
        for (int j = 0; j < 8; ++j) xb[j] = zbase[lane + 64 * j];
        // ---- stage WW (4KB, coalesced) ----
        if (tid < 128) {
            const int c = tid;
            const float4 wz0 = *(const float4*)&Wz[c * 8];
            const float4 wz1 = *(const float4*)&Wz[c * 8 + 4];
            const float lw = lzw[c];
            float wzv[8] = {wz0.x, wz0.y, wz0.z, wz0.w, wz1.x, wz1.y, wz1.z, wz1.w};
            #pragma unroll
            for (int h = 0; h < 8; ++h) {
                sW[h * 128 + c] = f2bf(lw * wzv[h]);
                sW[(8 + h) * 128 + c] = 0;
            }
        }
        __syncthreads();
        bf16x8 bfr[4];
        #pragma unroll
        for (int t = 0; t < 4; ++t)
            bfr[t] = *(const bf16x8*)&sW[rl * 128 + t * 32 + kg * 8];
        // ---- exact f32 stats: lane's float4 j belongs to row 2j+(lane>>5) ----
        const int hw = lane >> 5, c4 = lane & 31;
        float smj[8], sqj[8];
        #pragma unroll
        for (int j = 0; j < 8; ++j) {
            const float4 x = xb[j];
            smj[j] = x.x + x.y + x.z + x.w;
            sqj[j] = x.x*x.x + x.y*x.y + x.z*x.z + x.w*x.w;
        }
        #pragma unroll
        for (int j = 0; j < 8; ++j) {
            #pragma unroll
            for (int off = 1; off < 32; off <<= 1) {
                smj[j] += __shfl_xor(smj[j], off);
                sqj[j] += __shfl_xor(sqj[j], off);
            }
        }
        // ---- normalize in-register, convert, swizzled LDS store ----
        #pragma unroll
        for (int j = 0; j < 8; ++j) {
            const int r = 2 * j + hw;
            const float mu = smj[j] * (1.0f / CZ);
            const float var = sqj[j] * (1.0f / CZ) - mu * mu;
            const float rs = rsqrtf(var + 1e-5f);
            const float4 x = xb[j];
            u16 t4[4];
            t4[0] = f2bf((x.x - mu) * rs);
            t4[1] = f2bf((x.y - mu) * rs);
            t4[2] = f2bf((x.z - mu) * rs);
            t4[3] = f2bf((x.w - mu) * rs);
            *(ushort4_t*)&myZ[r * 128 + ((c4 >> 1) ^ (r & 7)) * 8 + (c4 & 1) * 4] =
                *(ushort4_t*)t4;
        }
        // ---- A-frags from swizzled LDS + MFMA; raw acc IS the logit ----
        bf16x8 af[4];
        #pragma unroll
        for (int t = 0; t < 4; ++t)
            af[t] = *(const bf16x8*)&myZ[rl * 128 + ((t * 4 + kg) ^ (rl & 7)) * 8];
        f32x4 acc = {};
        #pragma unroll
        for (int t = 0; t < 4; ++t)
            acc = __builtin_amdgcn_mfma_f32_16x16x32_bf16(af[t], bfr[t], acc, 0, 0, 0);
        if (rl < 8)
            *(f32x4*)&zb[(size_t)rl * NROW + row0 + kg * 4] = acc;
    } else if (bid < 2310) {
        float* sRed = (float*)SMEM;        // [4][64]
        const int k = (bid - 2304) * 64 + lane;
        float mx = -1e30f;
        #pragma unroll
        for (int i = 0; i < 16; ++i) {
            const int s = wave * 16 + i;
            mx = fmaxf(mx, mask[(size_t)s * NRES + k]);
        }
        sRed[wave * 64 + lane] = mx;
        __syncthreads();
        if (wave == 0) {
            mx = fmaxf(fmaxf(sRed[lane], sRed[64 + lane]),
                       fmaxf(sRed[128 + lane], sRed[192 + lane]));
            bias[k] = 1e9f * (mx - 1.0f);
        }
    } else if (bid < 2822) {
        const int i = (bid - 2310) * 256 + tid;
        const int n = i >> 8, k = i & 255;
        const float v = (n < HC) ? Wv[(size_t)k * HC + n] : Wg[(size_t)k * HC + (n - HC)];
        Wt[i] = f2bf(v);
    } else if (bid < 3078) {
        const int i = (bid - 2822) * 256 + tid;
        const int n = i >> 8, k = i & 255;
        Wot[i] = f2bf(Wo[(size_t)k * CM + n]);
    } else {
        // m_ln: 8 rows/block, 2 rows/wave, 32B per lane, 5-step half-wave reduce
        const int hw = lane >> 5, hl = lane & 31;
        const int row = (bid - 3078) * 8 + wave * 2 + hw;
        const float4 x0 = *(const float4*)&m[(size_t)row * CM + hl * 8];
        const float4 x1 = *(const float4*)&m[(size_t)row * CM + hl * 8 + 4];
        float sm = x0.x + x0.y + x0.z + x0.w + x1.x + x1.y + x1.z + x1.w;
        float sq = x0.x*x0.x + x0.y*x0.y + x0.z*x0.z + x0.w*x0.w
                 + x1.x*x1.x + x1.y*x1.y + x1.z*x1.z + x1.w*x1.w;
        #pragma unroll
        for (int off = 1; off < 32; off <<= 1) {
            sm += __shfl_xor(sm, off);
            sq += __shfl_xor(sq, off);
        }
        const float mu = sm * (1.0f / CM);
        const float var = sq * (1.0f / CM) - mu * mu;
        const float rs = rsqrtf(var + 1e-5f);
        const float4 w0 = *(const float4*)&lmw[hl * 8];
        const float4 w1 = *(const float4*)&lmw[hl * 8 + 4];
        const float4 b0 = *(const float4*)&lmb[hl * 8];
        const float4 b1 = *(const float4*)&lmb[hl * 8 + 4];
        u16 t8[8];
        t8[0] = f2bf((x0.x - mu) * rs * w0.x + b0.x);
        t8[1] = f2bf((x0.y - mu) * rs * w0.y + b0.y);
        t8[2] = f2bf((x0.z - mu) * rs * w0.z + b0.z);
        t8[3] = f2bf((x0.w - mu) * rs * w0.w + b0.w);
        t8[4] = f2bf((x1.x - mu) * rs * w1.x + b1.x);
        t8[5] = f2bf((x1.y - mu) * rs * w1.y + b1.y);
        t8[6] = f2bf((x1.z - mu) * rs * w1.z + b1.z);
        t8[7] = f2bf((x1.w - mu) * rs * w1.w + b1.w);
        *(ushort8*)&mln[(size_t)row * CM + hl * 8] = *(ushort8*)t8;
    }
}

// =====================  stage 2: gemm_vg | soft  =============================
__global__ __launch_bounds__(256) void k_stage2(
        const u16* __restrict__ mln, const u16* __restrict__ Wt,
        const float* __restrict__ zb, const float* __restrict__ bias,
        u16* __restrict__ vt, u16* __restrict__ g_, u16* __restrict__ a_out) {
    __shared__ u16 As[128][32];
    __shared__ u16 Bs[128][32];
    const int bid = blockIdx.x, tid = threadIdx.x;
    if (bid >= 768) {
        const int w = (bid - 768) * 4 + (tid >> 6);
        const int lane = tid & 63;
        const int h = w & 7, q = w >> 3;
        const float* zbh = zb + (size_t)h * NROW + (size_t)q * NRES;
        float v[6];
        float mx = -1e30f;
        #pragma unroll
        for (int t = 0; t < 6; ++t) {
            const int k = lane + 64 * t;
            v[t] = zbh[k] + bias[k];
            mx = fmaxf(mx, v[t]);
        }
        #pragma unroll
        for (int off = 32; off >= 1; off >>= 1) mx = fmaxf(mx, __shfl_xor(mx, off));
        float sum = 0.f;
        #pragma unroll
        for (int t = 0; t < 6; ++t) { v[t] = expf(v[t] - mx); sum += v[t]; }
        #pragma unroll
        for (int off = 32; off >= 1; off >>= 1) sum += __shfl_xor(sum, off);
        const float inv = 1.0f / sum;
        #pragma unroll
        for (int t = 0; t < 6; ++t)
            a_out[((size_t)h * NRES + q) * NRES + lane + 64 * t] = f2bf(v[t] * inv);
        return;
    }
    const int xcd = bid & 7, idx = bid >> 3;
    const int nt = idx & 3, mt = xcd * 24 + (idx >> 2);
    const int m0 = mt * 128, n0 = nt * 128;
    const int wave = tid >> 6, lane = tid & 63;
    const int wm = (wave >> 1) * 64, wn = (wave & 1) * 64;
    const int rl = lane & 15, kg = lane >> 4;
    const int lr = lane >> 2, lk = (lane & 3) * 8;
    const int wr = wave * 32;
    const u16* ag  = mln + (size_t)(m0 + wr + lr) * CM + lk;
    const u16* ag2 = ag + 16 * CM;
    const u16* bg  = Wt + (size_t)(n0 + wr + lr) * CM + lk;
    const u16* bg2 = bg + 16 * CM;
    u16* al  = &As[wr][0];
    u16* al2 = &As[wr + 16][0];
    u16* bl  = &Bs[wr][0];
    u16* bl2 = &Bs[wr + 16][0];
    const bool vhalf = (n0 < HC);
    f32x4 acc[4][4] = {};
    for (int kt = 0; kt < CM; kt += 32) {
        if (kt) __syncthreads();
        gload16(ag + kt, al);  gload16(ag2 + kt, al2);
        gload16(bg + kt, bl);  gload16(bg2 + kt, bl2);
        __syncthreads();
        bf16x8 af[4], bfr[4];
        #pragma unroll
        for (int i = 0; i < 4; ++i) af[i]  = *(const bf16x8*)&As[wm + i*16 + rl][kg*8];
        #pragma unroll
        for (int j = 0; j < 4; ++j) bfr[j] = *(const bf16x8*)&Bs[wn + j*16 + rl][kg*8];
        if (vhalf) {
            #pragma unroll
            for (int j = 0; j < 4; ++j)
                #pragma unroll
                for (int i = 0; i < 4; ++i)
                    acc[j][i] = __builtin_amdgcn_mfma_f32_16x16x32_bf16(bfr[j], af[i], acc[j][i], 0, 0, 0);
        } else {
            #pragma unroll
            for (int i = 0; i < 4; ++i)
                #pragma unroll
                for (int j = 0; j < 4; ++j)
                    acc[i][j] = __builtin_amdgcn_mfma_f32_16x16x32_bf16(af[i], bfr[j], acc[i][j], 0, 0, 0);
        }
    }
    if (vhalf) {
        #pragma unroll
        for (int j = 0; j < 4; ++j)
            #pragma unroll
            for (int r = 0; r < 4; ++r) {
                const int vcol = n0 + wn + j*16 + kg*4 + r;
                const int h = vcol >> 5, c = vcol & 31;
                #pragma unroll
                for (int i = 0; i < 4; ++i) {
                    const int mrowb = m0 + wm + i*16;
                    const int s = mrowb / NRES;
                    const int nn = mrowb - s * NRES + rl;
                    vt[(((size_t)h * S + s) * CH + c) * NRES + nn] = f2bf(acc[j][i][r]);
                }
            }
    } else {
        #pragma unroll
        for (int i = 0; i < 4; ++i)
            #pragma unroll
            for (int r = 0; r < 4; ++r) {
                const int row = m0 + wm + i*16 + kg*4 + r;
                #pragma unroll
                for (int j = 0; j < 4; ++j) {
                    const int gc = n0 + wn + j*16 + rl - HC;
                    g_[(size_t)row * HC + gc] = f2bf(1.0f / (1.0f + expf(-acc[i][j][r])));
                }
            }
    }
}

// ========== attn as per-h GEMM (one head per XCD), gload_lds staging =========
__global__ __launch_bounds__(256) void k_attn2(const u16* __restrict__ a_,
        const u16* __restrict__ vt, u16* __restrict__ o_) {
    __shared__ u16 As[128][32];
    __shared__ u16 Bs[128][32];
    const int tid = threadIdx.x;
    const int h = blockIdx.x & 7, rem = blockIdx.x >> 3;
    const int mt = rem >> 4, nt = rem & 15;
    const int q0 = mt * 128, sc0 = nt * 128;
    const int wave = tid >> 6, lane = tid & 63;
    const int wm = (wave >> 1) * 64, wn = (wave & 1) * 64;
    const int rl = lane & 15, kg = lane >> 4;
    const int lr = lane >> 2, lk = (lane & 3) * 8;
    const int wr = wave * 32;
    const u16* ag  = a_ + (size_t)h * NRES * NRES + (size_t)(q0 + wr + lr) * NRES + lk;
    const u16* ag2 = ag + 16 * NRES;
    const u16* bg  = vt + (size_t)h * S * CH * NRES + (size_t)(sc0 + wr + lr) * NRES + lk;
    const u16* bg2 = bg + 16 * NRES;
    u16* al  = &As[wr][0];
    u16* al2 = &As[wr + 16][0];
    u16* bl  = &Bs[wr][0];
    u16* bl2 = &Bs[wr + 16][0];
    f32x4 acc[4][4] = {};
    for (int kt = 0; kt < NRES; kt += 32) {
        if (kt) __syncthreads();
        gload16(ag + kt, al);  gload16(ag2 + kt, al2);
        gload16(bg + kt, bl);  gload16(bg2 + kt, bl2);
        __syncthreads();
        bf16x8 af[4], bfr[4];
        #pragma unroll
        for (int i = 0; i < 4; ++i) af[i]  = *(const bf16x8*)&As[wm + i*16 + rl][kg*8];
        #pragma unroll
        for (int j = 0; j < 4; ++j) bfr[j] = *(const bf16x8*)&Bs[wn + j*16 + rl][kg*8];
        #pragma unroll
        for (int i = 0; i < 4; ++i)
            #pragma unroll
            for (int j = 0; j < 4; ++j)
                acc[i][j] = __builtin_amdgcn_mfma_f32_16x16x32_bf16(af[i], bfr[j], acc[i][j], 0, 0, 0);
    }
    #pragma unroll
    for (int i = 0; i < 4; ++i)
        #pragma unroll
        for (int r = 0; r < 4; ++r) {
            const int q = q0 + wm + i*16 + kg*4 + r;
            #pragma unroll
            for (int j = 0; j < 4; ++j) {
                const int sc = sc0 + wn + j*16 + rl;
                const int s = sc >> 5, c = sc & 31;
                o_[(((size_t)s * NRES + q) * NH + h) * CH + c] = f2bf(acc[i][j][r]);
            }
        }
}

// ========== out = (o*g) @ Wo  (XCD-swizzled, B via gload_lds) ================
__global__ __launch_bounds__(256) void k_gemm_out(const u16* __restrict__ o_,
        const u16* __restrict__ g_, const u16* __restrict__ Wot,
        float* __restrict__ out) {
    __shared__ u16 As[128][40];
    __shared__ u16 Bs[128][32];
    const int tid = threadIdx.x;
    const int xcd = blockIdx.x & 7, idx = blockIdx.x >> 3;
    const int nt = idx & 1, mt = xcd * 24 + (idx >> 1);
    const int m0 = mt * 128, n0 = nt * 128;
    const int wave = tid >> 6, lane = tid & 63;
    const int wm = (wave >> 1) * 64, wn = (wave & 1) * 64;
    const int rl = lane & 15, kg = lane >> 4;
    const int lr = lane >> 2, lk = (lane & 3) * 8;
    const int wr = wave * 32;
    const int sr = tid >> 1, sh = (tid & 1) * 16;
    const u16* orow = o_ + (size_t)(m0 + sr) * HC;
    const u16* grow = g_ + (size_t)(m0 + sr) * HC;
    const u16* bg  = Wot + (size_t)(n0 + wr + lr) * HC + lk;
    const u16* bg2 = bg + 16 * HC;
    u16* bl  = &Bs[wr][0];
    u16* bl2 = &Bs[wr + 16][0];
    f32x4 acc[4][4] = {};
    for (int kt = 0; kt < HC; kt += 32) {
        if (kt) __syncthreads();
        gload16(bg + kt, bl);  gload16(bg2 + kt, bl2);
        {
            u16 tmp[16];
            const ushort8 ov0 = *(const ushort8*)&orow[kt + sh];
            const ushort8 ov1 = *(const ushort8*)&orow[kt + sh + 8];
            const ushort8 gv0 = *(const ushort8*)&grow[kt + sh];
            const ushort8 gv1 = *(const ushort8*)&grow[kt + sh + 8];
            #pragma unroll
            for (int p = 0; p < 8; ++p) {
                tmp[p]     = f2bf(bf2f(ov0[p]) * bf2f(gv0[p]));
                tmp[p + 8] = f2bf(bf2f(ov1[p]) * bf2f(gv1[p]));
            }
            *(ushort8*)&As[sr][sh]     = *(ushort8*)&tmp[0];
            *(ushort8*)&As[sr][sh + 8] = *(ushort8*)&tmp[8];
        }
        __syncthreads();
        bf16x8 af[4], bfr[4];
        #pragma unroll
        for (int i = 0; i < 4; ++i) af[i]  = *(const bf16x8*)&As[wm + i*16 + rl][kg*8];
        #pragma unroll
        for (int j = 0; j < 4; ++j) bfr[j] = *(const bf16x8*)&Bs[wn + j*16 + rl][kg*8];
        #pragma unroll
        for (int i = 0; i < 4; ++i)
            #pragma unroll
            for (int j = 0; j < 4; ++j)
                acc[i][j] = __builtin_amdgcn_mfma_f32_16x16x32_bf16(af[i], bfr[j], acc[i][j], 0, 0, 0);
    }
    #pragma unroll
    for (int i = 0; i < 4; ++i)
        #pragma unroll
        for (int r = 0; r < 4; ++r) {
            const int row = m0 + wm + i*16 + kg*4 + r;
            #pragma unroll
            for (int j = 0; j < 4; ++j)
                out[(size_t)row * CM + n0 + wn + j*16 + rl] = acc[i][j][r];
        }
}

extern "C" void kernel_launch(void* const* d_in, const int* in_sizes, int n_in,
                              void* d_out, int out_size, void* d_ws, size_t ws_size,
                              hipStream_t stream) {
    const float* m      = (const float*)d_in[0];
    const float* z      = (const float*)d_in[1];
    const float* mask   = (const float*)d_in[2];
    const float* ln_m_w = (const float*)d_in[3];
    const float* ln_m_b = (const float*)d_in[4];
    const float* ln_z_w = (const float*)d_in[5];
    const float* Wz     = (const float*)d_in[7];
    const float* Wv     = (const float*)d_in[8];
    const float* Wg     = (const float*)d_in[9];
    const float* Wo     = (const float*)d_in[10];
    float* out = (float*)d_out;
    char* ws = (char*)d_ws;

    float* bias = (float*)(ws + OFF_BIAS);
    u16* Wt     = (u16*)(ws + OFF_WT);
    u16* Wot    = (u16*)(ws + OFF_WOT);
    u16* a      = (u16*)(ws + OFF_A);
    u16* vtw    = (u16*)(ws + OFF_VT);
    u16* gw     = (u16*)(ws + OFF_G);
    u16* ow     = (u16*)(ws + OFF_O);
    u16* mlnw   = (u16*)(ws + OFF_MLN);
    float* zbw  = (float*)(ws + OFF_ZB);

    k_front<<<6150, 256, 0, stream>>>(z, Wz, ln_z_w, mask, Wv, Wg, Wo, m,
                                      ln_m_w, ln_m_b, zbw, bias, Wt, Wot, mlnw);
    k_stage2<<<1536, 256, 0, stream>>>(mlnw, Wt, zbw, bias, vtw, gw, a);
    k_attn2<<<384, 256, 0, stream>>>(a, vtw, ow);
    k_gemm_out<<<384, 256, 0, stream>>>(ow, gw, Wot, out);
}